// Round 19
// baseline (39.944 us; speedup 1.0000x reference)
//
#include <hip/hip_runtime.h>

namespace {
constexpr int kV    = 21;
constexpr int kNCh  = 1344;         // V*C_OUT
constexpr int kInner = kNCh * 256;  // 344064 elements per n

typedef float f32x4 __attribute__((ext_vector_type(4)));

// workspace layout (floats)
constexpr int X4_OFF = 0;            // [64][3][4][21] = 16128
constexpr int M_OFF  = 16384;        // [5376][9] = 48384
constexpr int U_OFF  = 65536;        // [5376][64][4] = 1376256
constexpr int ST_OFF = U_OFF + 5376 * 64 * 4;   // [1344][2]
}

// ---------------------------------------------------------------------------
// kA: X4[n][ci][q][v] = sum_{t=q*64..q*64+63} x[n][ci][t][v]
// ---------------------------------------------------------------------------
__global__ __launch_bounds__(256) void kA_x4(const float* __restrict__ x,
                                             float* __restrict__ x4) {
  __shared__ float ls[3][1344];
  __shared__ float part[252];
  int b = blockIdx.x;                 // 256 blocks
  int n = b >> 2, q = b & 3;
  int tid = threadIdx.x;
  for (int idx = tid; idx < 1008; idx += 256) {   // 1008 f32x4 total
    int ci = idx / 336;
    int off = idx - ci * 336;
    ((f32x4*)ls)[idx] =
        ((const f32x4*)(x + (n * 3 + ci) * 5376 + q * 1344))[off];
  }
  __syncthreads();
  if (tid < 252) {
    int ci = tid / 84, rest = tid - ci * 84;
    int tq = rest / 21, v = rest - tq * 21;
    float s = 0.f;
#pragma unroll
    for (int i = 0; i < 16; ++i) s += ls[ci][(tq * 16 + i) * 21 + v];
    part[tid] = s;
  }
  __syncthreads();
  if (tid < 63) {
    int ci = tid / 21, v = tid - ci * 21;
    const float* p = part + ci * 84 + v;
    x4[((n * 3 + ci) * 4 + q) * 21 + v] = p[0] + p[21] + p[42] + p[63];
  }
}

// ---------------------------------------------------------------------------
// kB: one block per r. S -> u (LDS) -> write U_all[t6][n][4] (coalesced)
// and per-(r,w) 9 float moments -> M
// ---------------------------------------------------------------------------
__global__ __launch_bounds__(256) void kB_mom(const float* __restrict__ x4,
                                              const float* __restrict__ A,
                                              const float* __restrict__ W,
                                              const float* __restrict__ bias,
                                              float* __restrict__ M,
                                              float* __restrict__ U_all) {
  __shared__ float Sld[64 * 65];        // S[n][k*21+v], pitch 65
  __shared__ float At[3 * 21 * 22];     // A_t[k][w][v], pitch 22
  __shared__ float Uld[64 * 65];        // u[n][w*3+k], pitch 65
  __shared__ float P[21 * 8 * 9];       // partial moments
  int r = blockIdx.x;
  int tid = threadIdx.x;

  for (int t = tid; t < 1323; t += 256) {   // At[k][w][v] = A[k][v][w]
    int k = t / 441, rem = t - k * 441;
    int v = rem / 21, w = rem - v * 21;
    At[k * 462 + w * 22 + v] = A[t];
  }
  for (int idx = tid; idx < 4032; idx += 256) {
    int n = idx / 63, kv = idx - n * 63;
    int k = kv / 21, v = kv - k * 21;
    int g = r * 3 + k;
    int o = g >> 2, q = g & 3;
    const float* xp = x4 + n * 252 + q * 21 + v;
    Sld[n * 65 + kv] = W[o * 3 + 0] * xp[0] + W[o * 3 + 1] * xp[84] +
                       W[o * 3 + 2] * xp[168] + 64.f * bias[o];
  }
  __syncthreads();
  for (int idx = tid; idx < 1344; idx += 256) {
    int n = idx & 63, w = idx >> 6;
    float u[3];
#pragma unroll
    for (int k = 0; k < 3; ++k) {
      const float* a = At + k * 462 + w * 22;
      const float* s = Sld + n * 65 + k * 21;
      float acc = 0.f;
#pragma unroll
      for (int v = 0; v < 21; ++v) acc += a[v] * s[v];
      Uld[n * 65 + w * 3 + k] = acc;
      u[k] = acc;
    }
    f32x4 uv = {u[0], u[1], u[2], 0.f};
    ((f32x4*)U_all)[(r * 21 + w) * 64 + n] = uv;   // lanes: consecutive n
  }
  __syncthreads();
  if (tid < 168) {
    int w = tid / 8, i = tid - w * 8;
    float acc[9] = {0, 0, 0, 0, 0, 0, 0, 0, 0};
    for (int dn = 0; dn < 8; ++dn) {
      int n = i * 8 + dn;
      float u0 = Uld[n * 65 + w * 3 + 0];
      float u1 = Uld[n * 65 + w * 3 + 1];
      float u2 = Uld[n * 65 + w * 3 + 2];
      acc[0] += u0 * u0; acc[1] += u0 * u1; acc[2] += u0 * u2;
      acc[3] += u1 * u1; acc[4] += u1 * u2; acc[5] += u2 * u2;
      acc[6] += u0;      acc[7] += u1;      acc[8] += u2;
    }
#pragma unroll
    for (int m = 0; m < 9; ++m) P[(w * 8 + i) * 9 + m] = acc[m];
  }
  __syncthreads();
  if (tid < 189) {
    int w = tid / 9, m = tid - w * 9;
    float s = 0.f;
#pragma unroll
    for (int i = 0; i < 8; ++i) s += P[(w * 8 + i) * 9 + m];
    M[(r * 21 + w) * 9 + m] = s;
  }
}

// ---------------------------------------------------------------------------
// kB2: per-channel BN stats from float moments. 4 channels/block, lane = co.
// ---------------------------------------------------------------------------
__global__ __launch_bounds__(256) void kB2_stats(
    const float* __restrict__ M, const float* __restrict__ W_emb,
    const float* __restrict__ b_emb, const float* __restrict__ pos,
    const float* __restrict__ gamma, const float* __restrict__ beta,
    float* __restrict__ stats) {
  int ch = blockIdx.x * 4 + (threadIdx.x >> 6);   // < 1344
  int co = threadIdx.x & 63;
  float we0 = W_emb[co * 3 + 0], we1 = W_emb[co * 3 + 1],
        we2 = W_emb[co * 3 + 2];
  float be = b_emb[co];
  float S1 = 0.f, S2 = 0.f;
#pragma unroll
  for (int j = 0; j < 4; ++j) {
    int t6 = ch * 4 + j;
    int w = t6 % 21;
    const float* m = M + t6 * 9;
    float c = be + pos[w * 64 + co];
    float lin = we0 * m[6] + we1 * m[7] + we2 * m[8];
    S1 += lin + 64.f * c;
    S2 += we0 * we0 * m[0] + 2.f * we0 * we1 * m[1] + 2.f * we0 * we2 * m[2] +
          we1 * we1 * m[3] + 2.f * we1 * we2 * m[4] + we2 * we2 * m[5] +
          2.f * c * lin + 64.f * c * c;
  }
#pragma unroll
  for (int off = 1; off < 64; off <<= 1) {
    S1 += __shfl_xor(S1, off);
    S2 += __shfl_xor(S2, off);
  }
  if (co == 0) {
    float mean = S1 * (1.f / 16384.f);
    float var = S2 * (1.f / 16384.f) - mean * mean;
    float inv = rsqrtf(var + 1e-5f);
    stats[ch * 2 + 0] = gamma[ch] * inv;
    stats[ch * 2 + 1] = beta[ch] - mean * gamma[ch] * inv;
  }
}

// ---------------------------------------------------------------------------
// kC: PURE STREAM, 5376 blocks = 168 bi x 32 n-groups (2 n each).
// 2x wave-level store parallelism vs R15. NT, dense 16B/lane.
// ---------------------------------------------------------------------------
__global__ __launch_bounds__(256) void kC_out(
    const float* __restrict__ U_all, const float* __restrict__ W_emb,
    const float* __restrict__ b_emb, const float* __restrict__ pos,
    const float* __restrict__ stats, float* __restrict__ out) {
  int b = blockIdx.x;                // 5376
  int bi = b % 168;
  int ng = b / 168;                  // 0..31 (2 n's each)
  int tid = threadIdx.x;
  int base = bi * 32;                // first t6
  int t6l_a = tid >> 4;              // 0..15
  int t6l_b = 16 + t6l_a;
  int co0 = (tid & 15) * 4;
  int cc_a = tid >> 6, cc_b = 4 + cc_a;
  int w_a = (base + t6l_a) % 21;
  int w_b = (base + t6l_b) % 21;
  float we4[4][3], cadd_a[4], cadd_b[4];
#pragma unroll
  for (int d = 0; d < 4; ++d) {
    we4[d][0] = W_emb[(co0 + d) * 3 + 0];
    we4[d][1] = W_emb[(co0 + d) * 3 + 1];
    we4[d][2] = W_emb[(co0 + d) * 3 + 2];
    float be = b_emb[co0 + d];
    cadd_a[d] = be + pos[w_a * 64 + co0 + d];
    cadd_b[d] = be + pos[w_b * 64 + co0 + d];
  }
  float sc_a = stats[(bi * 8 + cc_a) * 2 + 0];
  float sh_a = stats[(bi * 8 + cc_a) * 2 + 1];
  float sc_b = stats[(bi * 8 + cc_b) * 2 + 0];
  float sh_b = stats[(bi * 8 + cc_b) * 2 + 1];
  int n0 = ng * 2;
  const f32x4* Ua = (const f32x4*)U_all + (base + t6l_a) * 64 + n0;
  const f32x4* Ub = (const f32x4*)U_all + (base + t6l_b) * 64 + n0;
  size_t outbase = (size_t)n0 * kInner + bi * 2048 + tid * 4;
#pragma unroll
  for (int i = 0; i < 2; ++i) {
    f32x4 ua = Ua[i], ub = Ub[i];
    f32x4 oa, ob;
#pragma unroll
    for (int d = 0; d < 4; ++d) {
      oa[d] = (we4[d][0] * ua[0] + we4[d][1] * ua[1] + we4[d][2] * ua[2] +
               cadd_a[d]) * sc_a + sh_a;
      ob[d] = (we4[d][0] * ub[0] + we4[d][1] * ub[1] + we4[d][2] * ub[2] +
               cadd_b[d]) * sc_b + sh_b;
    }
    float* outp = out + outbase + (size_t)i * kInner;
    __builtin_nontemporal_store(oa, (f32x4*)outp);
    __builtin_nontemporal_store(ob, (f32x4*)(outp + 1024));
  }
}

extern "C" void kernel_launch(void* const* d_in, const int* in_sizes, int n_in,
                              void* d_out, int out_size, void* d_ws, size_t ws_size,
                              hipStream_t stream) {
  const float* x      = (const float*)d_in[0];
  const float* A      = (const float*)d_in[1];
  const float* conv_w = (const float*)d_in[2];
  const float* conv_b = (const float*)d_in[3];
  const float* W_emb  = (const float*)d_in[4];
  const float* b_emb  = (const float*)d_in[5];
  const float* pos    = (const float*)d_in[6];
  const float* gamma  = (const float*)d_in[7];
  const float* beta   = (const float*)d_in[8];
  float* out = (float*)d_out;
  float* ws  = (float*)d_ws;

  float* x4    = ws + X4_OFF;
  float* M     = ws + M_OFF;
  float* U_all = ws + U_OFF;
  float* stats = ws + ST_OFF;

  kA_x4<<<256, 256, 0, stream>>>(x, x4);
  kB_mom<<<256, 256, 0, stream>>>(x4, A, conv_w, conv_b, M, U_all);
  kB2_stats<<<336, 256, 0, stream>>>(M, W_emb, b_emb, pos, gamma, beta, stats);
  kC_out<<<5376, 256, 0, stream>>>(U_all, W_emb, b_emb, pos, stats, out);
}

// Round 20
// 38.589 us; speedup vs baseline: 1.0351x; 1.0351x over previous
//
#include <hip/hip_runtime.h>

namespace {
constexpr int kV    = 21;
constexpr int kNCh  = 1344;         // V*C_OUT
constexpr int kInner = kNCh * 256;  // 344064 elements per n

typedef float f32x4 __attribute__((ext_vector_type(4)));

// workspace layout (floats)
constexpr int X4_OFF = 0;            // [64][3][4][21] = 16128
constexpr int M_OFF  = 16384;        // [5376][9] = 48384
constexpr int U_OFF  = 65536;        // [5376][64][4] = 1376256
constexpr int ST_OFF = U_OFF + 5376 * 64 * 4;   // [1344][2]
}

// ---------------------------------------------------------------------------
// kA: X4[n][ci][q][v] = sum_{t=q*64..q*64+63} x[n][ci][t][v]
// ---------------------------------------------------------------------------
__global__ __launch_bounds__(256) void kA_x4(const float* __restrict__ x,
                                             float* __restrict__ x4) {
  __shared__ float ls[3][1344];
  __shared__ float part[252];
  int b = blockIdx.x;                 // 256 blocks
  int n = b >> 2, q = b & 3;
  int tid = threadIdx.x;
  for (int idx = tid; idx < 1008; idx += 256) {   // 1008 f32x4 total
    int ci = idx / 336;
    int off = idx - ci * 336;
    ((f32x4*)ls)[idx] =
        ((const f32x4*)(x + (n * 3 + ci) * 5376 + q * 1344))[off];
  }
  __syncthreads();
  if (tid < 252) {
    int ci = tid / 84, rest = tid - ci * 84;
    int tq = rest / 21, v = rest - tq * 21;
    float s = 0.f;
#pragma unroll
    for (int i = 0; i < 16; ++i) s += ls[ci][(tq * 16 + i) * 21 + v];
    part[tid] = s;
  }
  __syncthreads();
  if (tid < 63) {
    int ci = tid / 21, v = tid - ci * 21;
    const float* p = part + ci * 84 + v;
    x4[((n * 3 + ci) * 4 + q) * 21 + v] = p[0] + p[21] + p[42] + p[63];
  }
}

// ---------------------------------------------------------------------------
// kB: one block per r. S -> u (LDS) -> write U_all[t6][n][4] (coalesced)
// and per-(r,w) 9 float moments -> M
// ---------------------------------------------------------------------------
__global__ __launch_bounds__(256) void kB_mom(const float* __restrict__ x4,
                                              const float* __restrict__ A,
                                              const float* __restrict__ W,
                                              const float* __restrict__ bias,
                                              float* __restrict__ M,
                                              float* __restrict__ U_all) {
  __shared__ float Sld[64 * 65];        // S[n][k*21+v], pitch 65
  __shared__ float At[3 * 21 * 22];     // A_t[k][w][v], pitch 22
  __shared__ float Uld[64 * 65];        // u[n][w*3+k], pitch 65
  __shared__ float P[21 * 8 * 9];       // partial moments
  int r = blockIdx.x;
  int tid = threadIdx.x;

  for (int t = tid; t < 1323; t += 256) {   // At[k][w][v] = A[k][v][w]
    int k = t / 441, rem = t - k * 441;
    int v = rem / 21, w = rem - v * 21;
    At[k * 462 + w * 22 + v] = A[t];
  }
  for (int idx = tid; idx < 4032; idx += 256) {
    int n = idx / 63, kv = idx - n * 63;
    int k = kv / 21, v = kv - k * 21;
    int g = r * 3 + k;
    int o = g >> 2, q = g & 3;
    const float* xp = x4 + n * 252 + q * 21 + v;
    Sld[n * 65 + kv] = W[o * 3 + 0] * xp[0] + W[o * 3 + 1] * xp[84] +
                       W[o * 3 + 2] * xp[168] + 64.f * bias[o];
  }
  __syncthreads();
  for (int idx = tid; idx < 1344; idx += 256) {
    int n = idx & 63, w = idx >> 6;
    float u[3];
#pragma unroll
    for (int k = 0; k < 3; ++k) {
      const float* a = At + k * 462 + w * 22;
      const float* s = Sld + n * 65 + k * 21;
      float acc = 0.f;
#pragma unroll
      for (int v = 0; v < 21; ++v) acc += a[v] * s[v];
      Uld[n * 65 + w * 3 + k] = acc;
      u[k] = acc;
    }
    f32x4 uv = {u[0], u[1], u[2], 0.f};
    ((f32x4*)U_all)[(r * 21 + w) * 64 + n] = uv;   // lanes: consecutive n
  }
  __syncthreads();
  if (tid < 168) {
    int w = tid / 8, i = tid - w * 8;
    float acc[9] = {0, 0, 0, 0, 0, 0, 0, 0, 0};
    for (int dn = 0; dn < 8; ++dn) {
      int n = i * 8 + dn;
      float u0 = Uld[n * 65 + w * 3 + 0];
      float u1 = Uld[n * 65 + w * 3 + 1];
      float u2 = Uld[n * 65 + w * 3 + 2];
      acc[0] += u0 * u0; acc[1] += u0 * u1; acc[2] += u0 * u2;
      acc[3] += u1 * u1; acc[4] += u1 * u2; acc[5] += u2 * u2;
      acc[6] += u0;      acc[7] += u1;      acc[8] += u2;
    }
#pragma unroll
    for (int m = 0; m < 9; ++m) P[(w * 8 + i) * 9 + m] = acc[m];
  }
  __syncthreads();
  if (tid < 189) {
    int w = tid / 9, m = tid - w * 9;
    float s = 0.f;
#pragma unroll
    for (int i = 0; i < 8; ++i) s += P[(w * 8 + i) * 9 + m];
    M[(r * 21 + w) * 9 + m] = s;
  }
}

// ---------------------------------------------------------------------------
// kB2: per-channel BN stats from float moments. 4 channels/block, lane = co.
// ---------------------------------------------------------------------------
__global__ __launch_bounds__(256) void kB2_stats(
    const float* __restrict__ M, const float* __restrict__ W_emb,
    const float* __restrict__ b_emb, const float* __restrict__ pos,
    const float* __restrict__ gamma, const float* __restrict__ beta,
    float* __restrict__ stats) {
  int ch = blockIdx.x * 4 + (threadIdx.x >> 6);   // < 1344
  int co = threadIdx.x & 63;
  float we0 = W_emb[co * 3 + 0], we1 = W_emb[co * 3 + 1],
        we2 = W_emb[co * 3 + 2];
  float be = b_emb[co];
  float S1 = 0.f, S2 = 0.f;
#pragma unroll
  for (int j = 0; j < 4; ++j) {
    int t6 = ch * 4 + j;
    int w = t6 % 21;
    const float* m = M + t6 * 9;
    float c = be + pos[w * 64 + co];
    float lin = we0 * m[6] + we1 * m[7] + we2 * m[8];
    S1 += lin + 64.f * c;
    S2 += we0 * we0 * m[0] + 2.f * we0 * we1 * m[1] + 2.f * we0 * we2 * m[2] +
          we1 * we1 * m[3] + 2.f * we1 * we2 * m[4] + we2 * we2 * m[5] +
          2.f * c * lin + 64.f * c * c;
  }
#pragma unroll
  for (int off = 1; off < 64; off <<= 1) {
    S1 += __shfl_xor(S1, off);
    S2 += __shfl_xor(S2, off);
  }
  if (co == 0) {
    float mean = S1 * (1.f / 16384.f);
    float var = S2 * (1.f / 16384.f) - mean * mean;
    float inv = rsqrtf(var + 1e-5f);
    stats[ch * 2 + 0] = gamma[ch] * inv;
    stats[ch * 2 + 1] = beta[ch] - mean * gamma[ch] * inv;
  }
}

// ---------------------------------------------------------------------------
// kC: PURE STREAM. 2688 blocks = 168 bi x 16 n-groups (4 n each). No LDS,
// no barriers: per thread ~26 cached loads + 8 f32x4 U loads + 8 dense NT
// stores (16B/lane, fill-kernel pattern).
// ---------------------------------------------------------------------------
__global__ __launch_bounds__(256) void kC_out(
    const float* __restrict__ U_all, const float* __restrict__ W_emb,
    const float* __restrict__ b_emb, const float* __restrict__ pos,
    const float* __restrict__ stats, float* __restrict__ out) {
  int b = blockIdx.x;                // 2688
  int bi = b % 168;
  int ng = b / 168;                  // 0..15 (4 n's each)
  int tid = threadIdx.x;
  int base = bi * 32;                // first t6
  int t6l_a = tid >> 4;              // 0..15
  int t6l_b = 16 + t6l_a;
  int co0 = (tid & 15) * 4;
  int cc_a = tid >> 6, cc_b = 4 + cc_a;
  int w_a = (base + t6l_a) % 21;
  int w_b = (base + t6l_b) % 21;
  float we4[4][3], cadd_a[4], cadd_b[4];
#pragma unroll
  for (int d = 0; d < 4; ++d) {
    we4[d][0] = W_emb[(co0 + d) * 3 + 0];
    we4[d][1] = W_emb[(co0 + d) * 3 + 1];
    we4[d][2] = W_emb[(co0 + d) * 3 + 2];
    float be = b_emb[co0 + d];
    cadd_a[d] = be + pos[w_a * 64 + co0 + d];
    cadd_b[d] = be + pos[w_b * 64 + co0 + d];
  }
  float sc_a = stats[(bi * 8 + cc_a) * 2 + 0];
  float sh_a = stats[(bi * 8 + cc_a) * 2 + 1];
  float sc_b = stats[(bi * 8 + cc_b) * 2 + 0];
  float sh_b = stats[(bi * 8 + cc_b) * 2 + 1];
  int n0 = ng * 4;
  const f32x4* Ua = (const f32x4*)U_all + (base + t6l_a) * 64 + n0;
  const f32x4* Ub = (const f32x4*)U_all + (base + t6l_b) * 64 + n0;
  size_t outbase = (size_t)n0 * kInner + bi * 2048 + tid * 4;
#pragma unroll
  for (int i = 0; i < 4; ++i) {
    f32x4 ua = Ua[i], ub = Ub[i];
    f32x4 oa, ob;
#pragma unroll
    for (int d = 0; d < 4; ++d) {
      oa[d] = (we4[d][0] * ua[0] + we4[d][1] * ua[1] + we4[d][2] * ua[2] +
               cadd_a[d]) * sc_a + sh_a;
      ob[d] = (we4[d][0] * ub[0] + we4[d][1] * ub[1] + we4[d][2] * ub[2] +
               cadd_b[d]) * sc_b + sh_b;
    }
    float* outp = out + outbase + (size_t)i * kInner;
    __builtin_nontemporal_store(oa, (f32x4*)outp);
    __builtin_nontemporal_store(ob, (f32x4*)(outp + 1024));
  }
}

extern "C" void kernel_launch(void* const* d_in, const int* in_sizes, int n_in,
                              void* d_out, int out_size, void* d_ws, size_t ws_size,
                              hipStream_t stream) {
  const float* x      = (const float*)d_in[0];
  const float* A      = (const float*)d_in[1];
  const float* conv_w = (const float*)d_in[2];
  const float* conv_b = (const float*)d_in[3];
  const float* W_emb  = (const float*)d_in[4];
  const float* b_emb  = (const float*)d_in[5];
  const float* pos    = (const float*)d_in[6];
  const float* gamma  = (const float*)d_in[7];
  const float* beta   = (const float*)d_in[8];
  float* out = (float*)d_out;
  float* ws  = (float*)d_ws;

  float* x4    = ws + X4_OFF;
  float* M     = ws + M_OFF;
  float* U_all = ws + U_OFF;
  float* stats = ws + ST_OFF;

  kA_x4<<<256, 256, 0, stream>>>(x, x4);
  kB_mom<<<256, 256, 0, stream>>>(x4, A, conv_w, conv_b, M, U_all);
  kB2_stats<<<336, 256, 0, stream>>>(M, W_emb, b_emb, pos, gamma, beta, stats);
  kC_out<<<2688, 256, 0, stream>>>(U_all, W_emb, b_emb, pos, stats, out);
}